// Round 9
// baseline (120.785 us; speedup 1.0000x reference)
//
#include <hip/hip_runtime.h>

// Direct-to-fragment separable projector (no LDS, no barriers).
// R8 post-mortem: staged-LDS k_proj ~44us = LDS pipe (755MB b128 re-reads,
// 8x redundant sgx) + 20 barrier drains/block. R9: each lane computes its
// mfma_32x32x16 A/B fragment elements directly (frag elem j = one exp of
// atom kbase+hi*8+j at the lane's row/col) from wave-uniform float4 params.
// 2x exp redundancy but zero LDS traffic, zero syncthreads -> issue-bound
// (~16us floor). KSPLIT=47, per=432 (16-divisible, no tail predication),
// 752 blocks = one co-residency round at ~3 blocks/CU.

#define S 128
#define NS 47            // K-splits: 46 x 432 + 1 x 128 atoms, all /16
#define PER 432
#define BLOCK 256        // 4 waves; wave w owns 64x64 quadrant (w>>1, w&1)

typedef _Float16 f16;
typedef _Float16 f16x8 __attribute__((ext_vector_type(8)));
typedef float floatx16 __attribute__((ext_vector_type(16)));
typedef float floatx4 __attribute__((ext_vector_type(4)));

#if __has_builtin(__builtin_amdgcn_exp2f)
#define FAST_EXP2(x) __builtin_amdgcn_exp2f(x)
#else
#define FAST_EXP2(x) exp2f(x)
#endif
#if __has_builtin(__builtin_amdgcn_rcpf)
#define FAST_RCP(x) __builtin_amdgcn_rcpf(x)
#else
#define FAST_RCP(x) (1.0f / (x))
#endif

// P[b*A + a] = (x, y, k = -0.5*log2e/var, c2 = log2(dens/(2 pi var)))
__global__ __launch_bounds__(256) void k_prep(const float* __restrict__ mol,
                                              const float* __restrict__ stds,
                                              const float* __restrict__ dens,
                                              float4* __restrict__ P,
                                              int B, int A) {
    int idx = blockIdx.x * 256 + threadIdx.x;
    if (idx >= B * A) return;
    int a = idx % A;
    float x = mol[(size_t)idx * 3 + 0];
    float y = mol[(size_t)idx * 3 + 1];
    float v  = stds[a] * stds[a];
    float rv = FAST_RCP(v);
    P[idx] = make_float4(x, y, -0.72134752044448f * rv,
                         __log2f(dens[a] * 0.15915494309189535f * rv));
}

__global__ __launch_bounds__(BLOCK, 3) void k_proj(
    const float4* __restrict__ P,    // (B, A) packed params
    float* __restrict__ part,        // (B*NS, 128*128) partial images (raw frag order)
    int B, int A)
{
    const int ks   = blockIdx.x;
    const int b    = blockIdx.y;
    const int tid  = threadIdx.x;
    const int lane = tid & 63;
    const int wav  = tid >> 6;        // quadrant: rows (wav>>1)*64, cols (wav&1)*64
    const int l31  = lane & 31;
    const int hi   = lane >> 5;       // k-half of the fragment

    const int a0 = ks * PER;
    const int a1 = min(a0 + PER, A);
    const int nk = (a1 - a0) >> 4;    // ksteps of 16 atoms (exact, PER/128 are /16)

    const float py0 = (float)((wav >> 1) * 64 + l31) - 63.5f;   // A-row (tile 0)
    const float px0 = (float)((wav & 1) * 64 + l31) - 63.5f;    // B-col (tile 0)

    floatx16 acc00 = {0.f}, acc01 = {0.f}, acc10 = {0.f}, acc11 = {0.f};

    const float4* pp = P + (size_t)b * A + a0 + hi * 8;

    for (int s = 0; s < nk; ++s) {
        f16x8 A0, A1, B0, B1;
#pragma unroll
        for (int j = 0; j < 8; ++j) {
            float4 p = pp[j];                      // wave-uniform-ish, L1 broadcast
            float dy0 = py0 - p.y;
            float ea0 = FAST_EXP2(fmaf(p.z * dy0, dy0, p.w));   // coef folded in Gy
            float dy1 = dy0 + 32.0f;
            float ea1 = FAST_EXP2(fmaf(p.z * dy1, dy1, p.w));
            float dx0 = px0 - p.x;
            float eb0 = FAST_EXP2((p.z * dx0) * dx0);
            float dx1 = dx0 + 32.0f;
            float eb1 = FAST_EXP2((p.z * dx1) * dx1);
            A0[j] = (f16)ea0;  A1[j] = (f16)ea1;
            B0[j] = (f16)eb0;  B1[j] = (f16)eb1;
        }
        pp += 16;
        acc00 = __builtin_amdgcn_mfma_f32_32x32x16_f16(A0, B0, acc00, 0, 0, 0);
        acc01 = __builtin_amdgcn_mfma_f32_32x32x16_f16(A0, B1, acc01, 0, 0, 0);
        acc10 = __builtin_amdgcn_mfma_f32_32x32x16_f16(A1, B0, acc10, 0, 0, 0);
        acc11 = __builtin_amdgcn_mfma_f32_32x32x16_f16(A1, B1, acc11, 0, 0, 0);
    }

    // store raw fragments: float index = (wav*4 + q)*1024 + lane*16 + reg
    float* base = part + ((size_t)(b * NS + ks)) * (S * S) + (wav * 4) * 1024 + lane * 16;
    floatx16 accs[4] = {acc00, acc01, acc10, acc11};
#pragma unroll
    for (int q = 0; q < 4; ++q) {
        float* pq = base + q * 1024;
        *(floatx4*)(pq + 0)  = (floatx4){accs[q][0],  accs[q][1],  accs[q][2],  accs[q][3]};
        *(floatx4*)(pq + 4)  = (floatx4){accs[q][4],  accs[q][5],  accs[q][6],  accs[q][7]};
        *(floatx4*)(pq + 8)  = (floatx4){accs[q][8],  accs[q][9],  accs[q][10], accs[q][11]};
        *(floatx4*)(pq + 12) = (floatx4){accs[q][12], accs[q][13], accs[q][14], accs[q][15]};
    }
}

// sum NS partial images per batch, un-permute frag layout, write out.
__global__ __launch_bounds__(256) void k_reduce(const float* __restrict__ part,
                                                float* __restrict__ out) {
    const int b = blockIdx.z;
    const int f = blockIdx.x * 256 + threadIdx.x;     // 0..16383 frag-order index

    const float* src = part + (size_t)(b * NS) * (S * S) + f;
    float s0 = 0.f, s1 = 0.f;
    int s = 0;
    for (; s + 1 < NS; s += 2) {
        s0 += src[(size_t)s * (S * S)];
        s1 += src[(size_t)(s + 1) * (S * S)];
    }
    if (s < NS) s0 += src[(size_t)s * (S * S)];
    float sum = s0 + s1;

    // decode f = (w*4 + q)*1024 + lane*16 + reg
    const int reg  = f & 15;
    const int lane = (f >> 4) & 63;
    const int q    = (f >> 10) & 3;
    const int w    = f >> 12;
    // mfma_32x32 C/D: col = lane&31, row = (reg&3) + 8*(reg>>2) + 4*(lane>>5)
    const int row = (w >> 1) * 64 + (q >> 1) * 32 + (reg & 3) + 8 * (reg >> 2) + 4 * (lane >> 5);
    const int col = (w & 1) * 64 + (q & 1) * 32 + (lane & 31);
    out[((size_t)b * S + row) * S + col] = sum;
}

extern "C" void kernel_launch(void* const* d_in, const int* in_sizes, int n_in,
                              void* d_out, int out_size, void* d_ws, size_t ws_size,
                              hipStream_t stream) {
    const float* mol  = (const float*)d_in[0];
    const float* stds = (const float*)d_in[1];
    const float* dens = (const float*)d_in[2];
    float* out = (float*)d_out;

    const int A = in_sizes[1];             // 20000
    const int B = in_sizes[0] / (A * 3);   // 16

    char* ws = (char*)d_ws;
    float4* P = (float4*)ws;                              // B*A*16 = 5.12 MB
    size_t part_off = ((size_t)B * A * 16 + 255) & ~(size_t)255;
    float* part = (float*)(ws + part_off);                // B*NS*64KB = 49.3 MB

    k_prep<<<(B * A + 255) / 256, 256, 0, stream>>>(mol, stds, dens, P, B, A);
    k_proj<<<dim3(NS, B), dim3(BLOCK), 0, stream>>>(P, part, B, A);
    k_reduce<<<dim3((S * S) / 256, 1, B), dim3(256), 0, stream>>>(part, out);
}

// Round 10
// 107.221 us; speedup vs baseline: 1.1265x; 1.1265x over previous
//
#include <hip/hip_runtime.h>

// Direct-to-fragment separable projector v2 (LDS param cache + SW pipeline).
// R9 post-mortem: frag-direct k_proj 49.6us @ VALUBusy 43.6% -- global param
// loads unpipelined (VGPR=60, no prefetch regs) at 6 waves/CU => latency-bound.
// R10: (a) block-private LDS param cache (each (b,ks) block exclusively owns
// its 640 atoms; prep folded in, k_prep kernel dropped); (b) explicit 1-kstep
// register prefetch, x2-unrolled; (c) NS=32/PER=640 (all /16, partials 33MB).

#define S 128
#define NS 32            // K-splits: 31 x 640 + 1 x 160 atoms, both /16
#define PER 640
#define BLOCK 256        // 4 waves; wave w = 64x64 quadrant (rows w>>1, cols w&1)

typedef _Float16 f16;
typedef _Float16 f16x8 __attribute__((ext_vector_type(8)));
typedef float floatx16 __attribute__((ext_vector_type(16)));
typedef float floatx4 __attribute__((ext_vector_type(4)));

#if __has_builtin(__builtin_amdgcn_exp2f)
#define FAST_EXP2(x) __builtin_amdgcn_exp2f(x)
#else
#define FAST_EXP2(x) exp2f(x)
#endif
#if __has_builtin(__builtin_amdgcn_rcpf)
#define FAST_RCP(x) __builtin_amdgcn_rcpf(x)
#else
#define FAST_RCP(x) (1.0f / (x))
#endif

__global__ __launch_bounds__(BLOCK, 2) void k_proj(
    const float* __restrict__ mol,   // (B, A, 3)
    const float* __restrict__ stds,  // (A)
    const float* __restrict__ dens,  // (A)
    float* __restrict__ part,        // (B*NS, 128*128) partials, raw frag order
    int B, int A)
{
    __shared__ float4 sP[PER];       // (x, y, k=-0.5*log2e/var, c2=log2(coef))

    const int ks   = blockIdx.x;
    const int b    = blockIdx.y;
    const int tid  = threadIdx.x;
    const int lane = tid & 63;
    const int wav  = tid >> 6;
    const int l31  = lane & 31;
    const int hi   = lane >> 5;

    const int a0  = ks * PER;
    const int a1  = min(a0 + PER, A);
    const int cnt = a1 - a0;          // 640 or 160, both /16

    // one-time param staging (this block exclusively owns atoms [a0,a1))
    for (int i = tid; i < cnt; i += BLOCK) {
        const int a = a0 + i;
        const size_t idx = (size_t)b * A + a;
        float x  = mol[idx * 3 + 0];
        float y  = mol[idx * 3 + 1];
        float v  = stds[a] * stds[a];
        float rv = FAST_RCP(v);
        sP[i] = make_float4(x, y, -0.72134752044448f * rv,
                            __log2f(dens[a] * 0.15915494309189535f * rv));
    }
    __syncthreads();   // the only barrier in the kernel

    const float py0 = (float)((wav >> 1) * 64 + l31) - 63.5f;   // A-row, tile 0
    const float px0 = (float)((wav & 1) * 64 + l31) - 63.5f;    // B-col, tile 0

    floatx16 acc00 = {0.f}, acc01 = {0.f}, acc10 = {0.f}, acc11 = {0.f};

    const int nk = cnt >> 4;          // even (40 or 10)
    const float4* sp = sP + hi * 8;

    // one kstep of 16 atoms from params pp[0..7] (this lane's k-half)
    auto kstep = [&](const float4 (&pp)[8]) {
        f16x8 A0, A1, B0, B1;
#pragma unroll
        for (int j = 0; j < 8; ++j) {
            float4 p = pp[j];
            float dy0 = py0 - p.y;
            float ea0 = FAST_EXP2(fmaf(p.z * dy0, dy0, p.w));   // coef folded in Gy
            float dy1 = dy0 + 32.0f;
            float ea1 = FAST_EXP2(fmaf(p.z * dy1, dy1, p.w));
            float dx0 = px0 - p.x;
            float eb0 = FAST_EXP2((p.z * dx0) * dx0);
            float dx1 = dx0 + 32.0f;
            float eb1 = FAST_EXP2((p.z * dx1) * dx1);
            A0[j] = (f16)ea0;  A1[j] = (f16)ea1;
            B0[j] = (f16)eb0;  B1[j] = (f16)eb1;
        }
        acc00 = __builtin_amdgcn_mfma_f32_32x32x16_f16(A0, B0, acc00, 0, 0, 0);
        acc01 = __builtin_amdgcn_mfma_f32_32x32x16_f16(A0, B1, acc01, 0, 0, 0);
        acc10 = __builtin_amdgcn_mfma_f32_32x32x16_f16(A1, B0, acc10, 0, 0, 0);
        acc11 = __builtin_amdgcn_mfma_f32_32x32x16_f16(A1, B1, acc11, 0, 0, 0);
    };

    // software pipeline, unrolled x2 (nk even): prefetch kstep s+1 while
    // computing kstep s -- ds_read latency hidden inside the wave.
    float4 c[8], n[8];
#pragma unroll
    for (int j = 0; j < 8; ++j) c[j] = sp[j];
    for (int s = 0; s < nk; s += 2) {
        const float4* sp1 = sp + (size_t)(s + 1) * 16;
#pragma unroll
        for (int j = 0; j < 8; ++j) n[j] = sp1[j];     // prefetch s+1
        kstep(c);                                      // compute s
        if (s + 2 < nk) {
            const float4* sp2 = sp + (size_t)(s + 2) * 16;
#pragma unroll
            for (int j = 0; j < 8; ++j) c[j] = sp2[j]; // prefetch s+2
        }
        kstep(n);                                      // compute s+1
    }

    // store raw fragments: float index = (wav*4 + q)*1024 + lane*16 + reg
    float* base = part + ((size_t)(b * NS + ks)) * (S * S) + (wav * 4) * 1024 + lane * 16;
    floatx16 accs[4] = {acc00, acc01, acc10, acc11};
#pragma unroll
    for (int q = 0; q < 4; ++q) {
        float* pq = base + q * 1024;
        *(floatx4*)(pq + 0)  = (floatx4){accs[q][0],  accs[q][1],  accs[q][2],  accs[q][3]};
        *(floatx4*)(pq + 4)  = (floatx4){accs[q][4],  accs[q][5],  accs[q][6],  accs[q][7]};
        *(floatx4*)(pq + 8)  = (floatx4){accs[q][8],  accs[q][9],  accs[q][10], accs[q][11]};
        *(floatx4*)(pq + 12) = (floatx4){accs[q][12], accs[q][13], accs[q][14], accs[q][15]};
    }
}

// sum NS partial images per batch, un-permute frag layout, write out.
__global__ __launch_bounds__(256) void k_reduce(const float* __restrict__ part,
                                                float* __restrict__ out) {
    const int b = blockIdx.z;
    const int f = blockIdx.x * 256 + threadIdx.x;     // frag-order index

    const float* src = part + (size_t)(b * NS) * (S * S) + f;
    float s0 = 0.f, s1 = 0.f;
    for (int s = 0; s < NS; s += 2) {                 // NS even
        s0 += src[(size_t)s * (S * S)];
        s1 += src[(size_t)(s + 1) * (S * S)];
    }
    float sum = s0 + s1;

    // decode f = (w*4 + q)*1024 + lane*16 + reg
    const int reg  = f & 15;
    const int lane = (f >> 4) & 63;
    const int q    = (f >> 10) & 3;
    const int w    = f >> 12;
    // mfma_32x32 C/D: col = lane&31, row = (reg&3) + 8*(reg>>2) + 4*(lane>>5)
    const int row = (w >> 1) * 64 + (q >> 1) * 32 + (reg & 3) + 8 * (reg >> 2) + 4 * (lane >> 5);
    const int col = (w & 1) * 64 + (q & 1) * 32 + (lane & 31);
    out[((size_t)b * S + row) * S + col] = sum;
}

extern "C" void kernel_launch(void* const* d_in, const int* in_sizes, int n_in,
                              void* d_out, int out_size, void* d_ws, size_t ws_size,
                              hipStream_t stream) {
    const float* mol  = (const float*)d_in[0];
    const float* stds = (const float*)d_in[1];
    const float* dens = (const float*)d_in[2];
    float* out = (float*)d_out;

    const int A = in_sizes[1];             // 20000
    const int B = in_sizes[0] / (A * 3);   // 16

    float* part = (float*)d_ws;            // B*NS*64KB = 33.6 MB

    k_proj<<<dim3(NS, B), dim3(BLOCK), 0, stream>>>(mol, stds, dens, part, B, A);
    k_reduce<<<dim3((S * S) / 256, 1, B), dim3(256), 0, stream>>>(part, out);
}

// Round 12
// 94.331 us; speedup vs baseline: 1.2804x; 1.1366x over previous
//
#include <hip/hip_runtime.h>

// Direct-to-fragment separable projector v3 (pkrtz + strength-reduced args +
// f16 partials). R10: k_proj ~40us vs ~18us issue floor; j-body had 6 cvt/pack
// + redundant arg math; partials 33.6MB f32. R11: v_cvt_pkrtz packs pairs in
// one instr; arg(d+32) = arg(d) + 64t + 1024k (2 fma); partials stored f16
// (16.8MB, k_reduce reads f16x8). Fixed floor: harness ws-poison fill ~48us.
// R11 fix: bit_cast pkrtz's __fp16-vector return to our _Float16 vector type.

#define S 128
#define NS 32            // K-splits: 31 x 640 + 1 x 160 atoms, both /16
#define PER 640
#define BLOCK 256        // 4 waves; wave w = 64x64 quadrant (rows w>>1, cols w&1)

typedef _Float16 f16;
typedef _Float16 f16x2 __attribute__((ext_vector_type(2)));
typedef _Float16 f16x8 __attribute__((ext_vector_type(8)));
typedef float floatx16 __attribute__((ext_vector_type(16)));
typedef float floatx4 __attribute__((ext_vector_type(4)));

#if __has_builtin(__builtin_amdgcn_exp2f)
#define FAST_EXP2(x) __builtin_amdgcn_exp2f(x)
#else
#define FAST_EXP2(x) exp2f(x)
#endif
#if __has_builtin(__builtin_amdgcn_rcpf)
#define FAST_RCP(x) __builtin_amdgcn_rcpf(x)
#else
#define FAST_RCP(x) (1.0f / (x))
#endif

static __device__ __forceinline__ f16x2 PKRTZ(float a, float b) {
#if __has_builtin(__builtin_amdgcn_cvt_pkrtz)
    return __builtin_bit_cast(f16x2, __builtin_amdgcn_cvt_pkrtz(a, b));
#else
    return (f16x2){(f16)a, (f16)b};
#endif
}

union frag_u { f16x8 v; f16x2 h[4]; };

__global__ __launch_bounds__(BLOCK, 2) void k_proj(
    const float* __restrict__ mol,   // (B, A, 3)
    const float* __restrict__ stds,  // (A)
    const float* __restrict__ dens,  // (A)
    f16* __restrict__ part,          // (B*NS, 128*128) f16 partials, frag order
    int B, int A)
{
    __shared__ float4 sP[PER];       // (x, y, k=-0.5*log2e/var, c2=log2(coef))

    const int ks   = blockIdx.x;
    const int b    = blockIdx.y;
    const int tid  = threadIdx.x;
    const int lane = tid & 63;
    const int wav  = tid >> 6;
    const int l31  = lane & 31;
    const int hi   = lane >> 5;

    const int a0  = ks * PER;
    const int a1  = min(a0 + PER, A);
    const int cnt = a1 - a0;          // 640 or 160, both /16 (exact, no dead atoms)

    for (int i = tid; i < cnt; i += BLOCK) {
        const int a = a0 + i;
        const size_t idx = (size_t)b * A + a;
        float x  = mol[idx * 3 + 0];
        float y  = mol[idx * 3 + 1];
        float v  = stds[a] * stds[a];
        float rv = FAST_RCP(v);
        sP[i] = make_float4(x, y, -0.72134752044448f * rv,
                            __log2f(dens[a] * 0.15915494309189535f * rv));
    }
    __syncthreads();   // the only barrier

    const float py0 = (float)((wav >> 1) * 64 + l31) - 63.5f;   // A-row, tile 0
    const float px0 = (float)((wav & 1) * 64 + l31) - 63.5f;    // B-col, tile 0

    floatx16 acc00 = {0.f}, acc01 = {0.f}, acc10 = {0.f}, acc11 = {0.f};

    const int nk = cnt >> 4;          // even (40 or 10)
    const float4* sp = sP + hi * 8;

    // one kstep of 16 atoms; this lane's k-half params in pp[0..7].
    // arg(d+32) = arg(d) + 64*(k*d) + 1024*k  -> 2 fma instead of sub+mul+fma.
    auto kstep = [&](const float4 (&pp)[8]) {
        frag_u A0, A1, B0, B1;
#pragma unroll
        for (int jp = 0; jp < 4; ++jp) {
            float ea0[2], ea1[2], eb0[2], eb1[2];
#pragma unroll
            for (int u = 0; u < 2; ++u) {
                float4 p = pp[2 * jp + u];
                float dy = py0 - p.y;
                float t  = p.z * dy;
                float g0 = fmaf(t, dy, p.w);
                float g1 = fmaf(1024.0f, p.z, fmaf(64.0f, t, g0));
                ea0[u] = FAST_EXP2(g0);
                ea1[u] = FAST_EXP2(g1);
                float dx = px0 - p.x;
                float s  = p.z * dx;
                float h0 = s * dx;
                float h1 = fmaf(1024.0f, p.z, fmaf(64.0f, s, h0));
                eb0[u] = FAST_EXP2(h0);
                eb1[u] = FAST_EXP2(h1);
            }
            A0.h[jp] = PKRTZ(ea0[0], ea0[1]);
            A1.h[jp] = PKRTZ(ea1[0], ea1[1]);
            B0.h[jp] = PKRTZ(eb0[0], eb0[1]);
            B1.h[jp] = PKRTZ(eb1[0], eb1[1]);
        }
        acc00 = __builtin_amdgcn_mfma_f32_32x32x16_f16(A0.v, B0.v, acc00, 0, 0, 0);
        acc01 = __builtin_amdgcn_mfma_f32_32x32x16_f16(A0.v, B1.v, acc01, 0, 0, 0);
        acc10 = __builtin_amdgcn_mfma_f32_32x32x16_f16(A1.v, B0.v, acc10, 0, 0, 0);
        acc11 = __builtin_amdgcn_mfma_f32_32x32x16_f16(A1.v, B1.v, acc11, 0, 0, 0);
    };

    // software pipeline, x2-unrolled (nk even): prefetch next kstep's params
    float4 c[8], n[8];
#pragma unroll
    for (int j = 0; j < 8; ++j) c[j] = sp[j];
    for (int s = 0; s < nk; s += 2) {
        const float4* sp1 = sp + (size_t)(s + 1) * 16;
#pragma unroll
        for (int j = 0; j < 8; ++j) n[j] = sp1[j];
        kstep(c);
        if (s + 2 < nk) {
            const float4* sp2 = sp + (size_t)(s + 2) * 16;
#pragma unroll
            for (int j = 0; j < 8; ++j) c[j] = sp2[j];
        }
        kstep(n);
    }

    // f16 partial store, raw frag order: idx = (wav*4+q)*1024 + lane*16 + reg
    f16* base = part + ((size_t)(b * NS + ks)) * (S * S) + (wav * 4) * 1024 + lane * 16;
    floatx16 accs[4] = {acc00, acc01, acc10, acc11};
#pragma unroll
    for (int q = 0; q < 4; ++q) {
        frag_u lo, hiv;
#pragma unroll
        for (int jp = 0; jp < 4; ++jp) {
            lo.h[jp]  = PKRTZ(accs[q][2 * jp],     accs[q][2 * jp + 1]);
            hiv.h[jp] = PKRTZ(accs[q][2 * jp + 8], accs[q][2 * jp + 9]);
        }
        *(f16x8*)(base + q * 1024 + 0) = lo.v;
        *(f16x8*)(base + q * 1024 + 8) = hiv.v;
    }
}

// sum NS f16 partials per batch (f16x8 coalesced reads), un-permute, write f32.
__global__ __launch_bounds__(256) void k_reduce(const f16* __restrict__ part,
                                                float* __restrict__ out) {
    const int b  = blockIdx.z;
    const int f8 = (blockIdx.x * 256 + threadIdx.x) * 8;   // frag-order base idx

    const f16* src = part + (size_t)b * NS * (S * S) + f8;
    float sum[8] = {0.f};
    for (int s = 0; s < NS; ++s) {
        f16x8 v = *(const f16x8*)&src[(size_t)s * (S * S)];
#pragma unroll
        for (int i = 0; i < 8; ++i) sum[i] += (float)v[i];
    }

    // decode f8 = (w*4+q)*1024 + lane*16 + reg0 (reg0 in {0,8})
    const int reg0 = f8 & 15;
    const int lane = (f8 >> 4) & 63;
    const int q    = (f8 >> 10) & 3;
    const int w    = f8 >> 12;
    // mfma_32x32 C/D: col = lane&31, row = (reg&3) + 8*(reg>>2) + 4*(lane>>5)
    const int rowb = (w >> 1) * 64 + (q >> 1) * 32 + 4 * (lane >> 5);
    const int col  = (w & 1) * 64 + (q & 1) * 32 + (lane & 31);
#pragma unroll
    for (int i = 0; i < 8; ++i) {
        const int reg = reg0 + i;
        const int row = rowb + (reg & 3) + 8 * (reg >> 2);
        out[((size_t)b * S + row) * S + col] = sum[i];
    }
}

extern "C" void kernel_launch(void* const* d_in, const int* in_sizes, int n_in,
                              void* d_out, int out_size, void* d_ws, size_t ws_size,
                              hipStream_t stream) {
    const float* mol  = (const float*)d_in[0];
    const float* stds = (const float*)d_in[1];
    const float* dens = (const float*)d_in[2];
    float* out = (float*)d_out;

    const int A = in_sizes[1];             // 20000
    const int B = in_sizes[0] / (A * 3);   // 16

    f16* part = (f16*)d_ws;                // B*NS*16384*2 = 16.8 MB

    k_proj<<<dim3(NS, B), dim3(BLOCK), 0, stream>>>(mol, stds, dens, part, B, A);
    k_reduce<<<dim3((S * S) / (256 * 8), 1, B), dim3(256), 0, stream>>>(part, out);
}